// Round 8
// baseline (60.209 us; speedup 1.0000x reference)
//
#include <hip/hip_runtime.h>

static constexpr int kNodes   = 100000;
static constexpr int kEdges   = 1600000;
static constexpr int kPairs   = kEdges / 2;      // 2 edges (one fx4 out) per pair
static constexpr int kD       = 128;
static constexpr int kBlocks  = 1024;
static constexpr int kThreads = kBlocks * 256;   // 262144
static constexpr int kLeaves  = 16;
static constexpr int kQuota   = kBlocks / kLeaves;

typedef float              fx4 __attribute__((ext_vector_type(4)));
typedef unsigned long long u64;

// ---------------------------------------------------------------------------
// 2-level grid barrier. leaves[i*16] (128B apart) count arrivals per residue
// class; last arriver at a leaf bumps root. Thread 0 polls root relaxed with
// s_sleep backoff, then one agent-scope acquire fence covers the whole block
// (same CU L1 / same XCD L2). Counters are zeroed by a hipMemsetAsync each
// launch, so no generation logic is needed (graph replays serialize).
// ---------------------------------------------------------------------------
__device__ inline void grid_barrier(u64* __restrict__ leaves,
                                    u64* __restrict__ root) {
    __syncthreads();   // all of this block's uv stores are retired
    if (threadIdx.x == 0) {
        const int leaf = blockIdx.x & (kLeaves - 1);
        u64 old = __hip_atomic_fetch_add(&leaves[leaf * 16], 1ull,
                                         __ATOMIC_RELEASE,
                                         __HIP_MEMORY_SCOPE_AGENT);
        if (old == (u64)(kQuota - 1)) {
            __hip_atomic_fetch_add(root, 1ull, __ATOMIC_RELEASE,
                                   __HIP_MEMORY_SCOPE_AGENT);
        }
        while (__hip_atomic_load(root, __ATOMIC_RELAXED,
                                 __HIP_MEMORY_SCOPE_AGENT) < (u64)kLeaves) {
            __builtin_amdgcn_s_sleep(8);
        }
        __builtin_amdgcn_fence(__ATOMIC_ACQUIRE, "agent");
    }
    __syncthreads();
}

// ---------------------------------------------------------------------------
// Fused kernel.
// Phase A: uv[2n]=emb[n]·(W1-W0)[:128], uv[2n+1]=emb[n]·(W1-W0)[128:]
//          (16 lanes/node, grid-stride ~6 nodes/group).
// Prefetch: up to 4 edge-pairs' indices issued as raw loads (no use -> no
//          waitcnt until after the barrier; the 25.6MB idx stream overlaps
//          phase-A stragglers and the barrier wait).
// Barrier: 2-level atomic tree (above).
// Phase C: d = u[r]+v[c]+db; p0 = 1/(1+e^d); out = {p0,1-p0} x2 per fx4.
// ---------------------------------------------------------------------------
__global__ __launch_bounds__(256, 4) void fused(const float* __restrict__ emb,
                                                const void* __restrict__ eiv,
                                                const float* __restrict__ W,
                                                const float* __restrict__ b,
                                                u64* __restrict__ flags,
                                                float* __restrict__ uv,
                                                float* __restrict__ out) {
    const int tid = blockIdx.x * 256 + threadIdx.x;
    const int l   = threadIdx.x & 15;
    const int c0  = l * 8;

    // ---- phase A ----
    {
        fx4 w0a = *(const fx4*)&W[c0],       w0b = *(const fx4*)&W[c0 + 4];
        fx4 w1a = *(const fx4*)&W[256 + c0], w1b = *(const fx4*)&W[256 + c0 + 4];
        fx4 dua = w1a - w0a, dub = w1b - w0b;
        fx4 w2a = *(const fx4*)&W[128 + c0], w2b = *(const fx4*)&W[128 + c0 + 4];
        fx4 w3a = *(const fx4*)&W[384 + c0], w3b = *(const fx4*)&W[384 + c0 + 4];
        fx4 dva = w3a - w2a, dvb = w3b - w2b;

        const int group   = tid >> 4;
        const int ngroups = kThreads >> 4;
        for (int n = group; n < kNodes; n += ngroups) {
            const fx4* row = (const fx4*)(emb + (size_t)n * kD + c0);
            fx4 ea = row[0];
            fx4 eb = row[1];
            float pu = ea.x*dua.x + ea.y*dua.y + ea.z*dua.z + ea.w*dua.w
                     + eb.x*dub.x + eb.y*dub.y + eb.z*dub.z + eb.w*dub.w;
            float pv = ea.x*dva.x + ea.y*dva.y + ea.z*dva.z + ea.w*dva.w
                     + eb.x*dvb.x + eb.y*dvb.y + eb.z*dvb.z + eb.w*dvb.w;
            float keep = (l & 1) ? pv : pu;
            float send = (l & 1) ? pu : pv;
            float x = keep + __shfl_xor(send, 1);
            x += __shfl_xor(x, 2);
            x += __shfl_xor(x, 4);
            x += __shfl_xor(x, 8);
            if (l < 2) uv[n * 2 + l] = x;
        }
    }

    // ---- dtype detect + edge-index prefetch (issued before the barrier) ----
    const u64* ei64 = (const u64*)eiv;
    u64 hi = ei64[threadIdx.x & 63] >> 32;
    const bool is64 = (__ballot(hi != 0ull) == 0ull);

    const float db = b[1] - b[0];
    u64* root = flags + 15 * 16 + 16;   // past the 16 leaf slots

    if (is64) {
        u64 rbuf[8], cbuf[8];           // raw, converted only after barrier
#pragma unroll
        for (int k = 0; k < 4; ++k) {
            int p = tid + k * kThreads;
            if (p < kPairs) {
                rbuf[2*k]   = ei64[2 * p];
                rbuf[2*k+1] = ei64[2 * p + 1];
                cbuf[2*k]   = ei64[kEdges + 2 * p];
                cbuf[2*k+1] = ei64[kEdges + 2 * p + 1];
            }
        }
        grid_barrier(flags, root);
#pragma unroll
        for (int k = 0; k < 4; ++k) {
            int p = tid + k * kThreads;
            if (p < kPairs) {
                int r0 = (int)rbuf[2*k], r1 = (int)rbuf[2*k+1];
                int cc0 = (int)cbuf[2*k], cc1 = (int)cbuf[2*k+1];
                float d0 = uv[2 * r0] + uv[2 * cc0 + 1] + db;
                float d1 = uv[2 * r1] + uv[2 * cc1 + 1] + db;
                float p00 = __builtin_amdgcn_rcpf(1.0f + __expf(d0));
                float p10 = __builtin_amdgcn_rcpf(1.0f + __expf(d1));
                fx4 o = {p00, 1.0f - p00, p10, 1.0f - p10};
                ((fx4*)out)[p] = o;
            }
        }
    } else {
        const int* ei32 = (const int*)eiv;
        int rbuf[8], cbuf[8];
#pragma unroll
        for (int k = 0; k < 4; ++k) {
            int p = tid + k * kThreads;
            if (p < kPairs) {
                rbuf[2*k]   = ei32[2 * p];
                rbuf[2*k+1] = ei32[2 * p + 1];
                cbuf[2*k]   = ei32[kEdges + 2 * p];
                cbuf[2*k+1] = ei32[kEdges + 2 * p + 1];
            }
        }
        grid_barrier(flags, root);
#pragma unroll
        for (int k = 0; k < 4; ++k) {
            int p = tid + k * kThreads;
            if (p < kPairs) {
                int r0 = rbuf[2*k], r1 = rbuf[2*k+1];
                int cc0 = cbuf[2*k], cc1 = cbuf[2*k+1];
                float d0 = uv[2 * r0] + uv[2 * cc0 + 1] + db;
                float d1 = uv[2 * r1] + uv[2 * cc1 + 1] + db;
                float p00 = __builtin_amdgcn_rcpf(1.0f + __expf(d0));
                float p10 = __builtin_amdgcn_rcpf(1.0f + __expf(d1));
                fx4 o = {p00, 1.0f - p00, p10, 1.0f - p10};
                ((fx4*)out)[p] = o;
            }
        }
    }
}

// ---------------------------------------------------------------------------
// Fallback: proven R7 two-kernel path (used only if the memset errors).
// ---------------------------------------------------------------------------
__global__ __launch_bounds__(256) void node_pre(const float* __restrict__ emb,
                                                const float* __restrict__ W,
                                                float* __restrict__ uv) {
    const int l  = threadIdx.x & 15;
    const int c0 = l * 8;
    fx4 w0a = *(const fx4*)&W[c0],       w0b = *(const fx4*)&W[c0 + 4];
    fx4 w1a = *(const fx4*)&W[256 + c0], w1b = *(const fx4*)&W[256 + c0 + 4];
    fx4 dua = w1a - w0a, dub = w1b - w0b;
    fx4 w2a = *(const fx4*)&W[128 + c0], w2b = *(const fx4*)&W[128 + c0 + 4];
    fx4 w3a = *(const fx4*)&W[384 + c0], w3b = *(const fx4*)&W[384 + c0 + 4];
    fx4 dva = w3a - w2a, dvb = w3b - w2b;

    const int n = (blockIdx.x * blockDim.x + threadIdx.x) >> 4;
    if (n >= kNodes) return;
    const fx4* row = (const fx4*)(emb + (size_t)n * kD + c0);
    fx4 ea = row[0];
    fx4 eb = row[1];
    float pu = ea.x*dua.x + ea.y*dua.y + ea.z*dua.z + ea.w*dua.w
             + eb.x*dub.x + eb.y*dub.y + eb.z*dub.z + eb.w*dub.w;
    float pv = ea.x*dva.x + ea.y*dva.y + ea.z*dva.z + ea.w*dva.w
             + eb.x*dvb.x + eb.y*dvb.y + eb.z*dvb.z + eb.w*dvb.w;
    float keep = (l & 1) ? pv : pu;
    float send = (l & 1) ? pu : pv;
    float x = keep + __shfl_xor(send, 1);
    x += __shfl_xor(x, 2);
    x += __shfl_xor(x, 4);
    x += __shfl_xor(x, 8);
    if (l < 2) uv[n * 2 + l] = x;
}

__global__ __launch_bounds__(256) void edge_attn(const void* __restrict__ eiv,
                                                 const float* __restrict__ uv,
                                                 const float* __restrict__ b,
                                                 float* __restrict__ out) {
    const u64* ei64 = (const u64*)eiv;
    u64 hi = ei64[threadIdx.x & 63] >> 32;
    const bool is64 = (__ballot(hi != 0ull) == 0ull);

    const int e2 = blockIdx.x * blockDim.x + threadIdx.x;
    if (e2 >= kPairs) return;

    int r0, r1, c0i, c1i;
    if (is64) {
        r0  = (int)ei64[2 * e2];          r1  = (int)ei64[2 * e2 + 1];
        c0i = (int)ei64[kEdges + 2 * e2]; c1i = (int)ei64[kEdges + 2 * e2 + 1];
    } else {
        const int* ei32 = (const int*)eiv;
        r0  = ei32[2 * e2];          r1  = ei32[2 * e2 + 1];
        c0i = ei32[kEdges + 2 * e2]; c1i = ei32[kEdges + 2 * e2 + 1];
    }
    const float db = b[1] - b[0];
    float d0 = uv[2 * r0] + uv[2 * c0i + 1] + db;
    float d1 = uv[2 * r1] + uv[2 * c1i + 1] + db;
    float p00 = __builtin_amdgcn_rcpf(1.0f + __expf(d0));
    float p10 = __builtin_amdgcn_rcpf(1.0f + __expf(d1));
    fx4 o = {p00, 1.0f - p00, p10, 1.0f - p10};
    ((fx4*)out)[e2] = o;
}

extern "C" void kernel_launch(void* const* d_in, const int* in_sizes, int n_in,
                              void* d_out, int out_size, void* d_ws, size_t ws_size,
                              hipStream_t stream) {
    const float* emb = (const float*)d_in[0];
    const void*  ei  = d_in[1];
    const float* W   = (const float*)d_in[2];
    const float* b   = (const float*)d_in[3];
    float* out = (float*)d_out;

    u64*   flags = (u64*)d_ws;                       // 16 leaves @128B + root
    float* uv    = (float*)((char*)d_ws + 8192);     // 800 KB node table

    hipError_t err = hipMemsetAsync(d_ws, 0, 4096, stream);
    if (err == hipSuccess) {
        fused<<<kBlocks, 256, 0, stream>>>(emb, ei, W, b, flags, uv, out);
    } else {
        node_pre<<<(kNodes * 16 + 255) / 256, 256, 0, stream>>>(emb, W, uv);
        edge_attn<<<(kPairs + 255) / 256, 256, 0, stream>>>(ei, uv, b, out);
    }
}

// Round 9
// 38.602 us; speedup vs baseline: 1.5597x; 1.5597x over previous
//
#include <hip/hip_runtime.h>

static constexpr int kNodes   = 100000;
static constexpr int kEdges   = 1600000;
static constexpr int kPairs   = kEdges / 2;      // 800000
static constexpr int kD       = 128;
static constexpr int kBlocks  = 1024;
static constexpr int kThreads = kBlocks * 256;   // 262144
static constexpr int kLeaves  = 16;
static constexpr int kQuota   = kBlocks / kLeaves;   // 64

typedef float              fx4 __attribute__((ext_vector_type(4)));
typedef unsigned long long u64;

// ---------------------------------------------------------------------------
// Cheap grid barrier: NO wbl2 / NO L2 invalidate anywhere.
// Preconditions: uv was written with sc1 (agent-scope relaxed) stores, which
// are L3-visible once vmcnt retires; __syncthreads() drains each wave's
// vmcnt (compiler emits s_waitcnt vmcnt(0) before s_barrier). So a relaxed
// arrival RMW is a correct release, and readers need no cache invalidate
// (their L2s never held uv lines). The workgroup-scope acquire fence is
// waitcnt-only: it orders phase-C loads after the spin without cache ops.
// ---------------------------------------------------------------------------
__device__ inline void grid_barrier(u64* __restrict__ leaves,
                                    u64* __restrict__ root) {
    __syncthreads();   // drains vmcnt per wave -> block's sc1 stores at L3
    if (threadIdx.x == 0) {
        const int leaf = blockIdx.x & (kLeaves - 1);
        u64 old = __hip_atomic_fetch_add(&leaves[leaf * 16], 1ull,
                                         __ATOMIC_RELAXED,
                                         __HIP_MEMORY_SCOPE_AGENT);
        if (old == (u64)(kQuota - 1)) {
            __hip_atomic_fetch_add(root, 1ull, __ATOMIC_RELAXED,
                                   __HIP_MEMORY_SCOPE_AGENT);
        }
        int guard = 0;
        while (__hip_atomic_load(root, __ATOMIC_RELAXED,
                                 __HIP_MEMORY_SCOPE_AGENT) < (u64)kLeaves) {
            __builtin_amdgcn_s_sleep(16);
            if (++guard > 100000) break;   // safety: fail loud, don't hang
        }
        __builtin_amdgcn_fence(__ATOMIC_ACQUIRE, "workgroup"); // order-only
    }
    __syncthreads();
}

__device__ inline void emit_pair(const float* __restrict__ uv,
                                 float* __restrict__ out, float db,
                                 int r0, int r1, int c0, int c1, int p) {
    float d0 = uv[2 * r0] + uv[2 * c0 + 1] + db;
    float d1 = uv[2 * r1] + uv[2 * c1 + 1] + db;
    float q0 = __builtin_amdgcn_rcpf(1.0f + __expf(d0));
    float q1 = __builtin_amdgcn_rcpf(1.0f + __expf(d1));
    fx4 o = {q0, 1.0f - q0, q1, 1.0f - q1};
    ((fx4*)out)[p] = o;
}

// ---------------------------------------------------------------------------
// Fused kernel.
// Phase A: uv[2n]=emb[n]·(W1-W0)[:128], uv[2n+1]=emb[n]·(W1-W0)[128:]
//          16 lanes/node, grid-stride; lane0 packs both into one u64 and
//          stores with AGENT-scope relaxed atomic (sc1 -> lands in L3).
// Prefetch: stripes 0,1 of edge indices loaded to regs, pinned live with
//          asm volatile so the compiler cannot sink them past the barrier.
// Barrier: relaxed 2-level tree (above), no cache maintenance.
// Phase C: d = u[r]+v[c]+db; p0 = 1/(1+e^d). Normal cached uv gathers
//          (L2 accumulates the 800KB table per XCD).
// ---------------------------------------------------------------------------
__global__ __launch_bounds__(256, 4) void fused(const float* __restrict__ emb,
                                                const void* __restrict__ eiv,
                                                const float* __restrict__ W,
                                                const float* __restrict__ b,
                                                u64* __restrict__ flags,
                                                float* __restrict__ uv,
                                                float* __restrict__ out) {
    const int tid = blockIdx.x * 256 + threadIdx.x;
    const int l   = threadIdx.x & 15;
    const int c0  = l * 8;

    // ---- phase A ----
    {
        fx4 w0a = *(const fx4*)&W[c0],       w0b = *(const fx4*)&W[c0 + 4];
        fx4 w1a = *(const fx4*)&W[256 + c0], w1b = *(const fx4*)&W[256 + c0 + 4];
        fx4 dua = w1a - w0a, dub = w1b - w0b;
        fx4 w2a = *(const fx4*)&W[128 + c0], w2b = *(const fx4*)&W[128 + c0 + 4];
        fx4 w3a = *(const fx4*)&W[384 + c0], w3b = *(const fx4*)&W[384 + c0 + 4];
        fx4 dva = w3a - w2a, dvb = w3b - w2b;

        const int group   = tid >> 4;
        const int ngroups = kThreads >> 4;
        for (int n = group; n < kNodes; n += ngroups) {
            const fx4* row = (const fx4*)(emb + (size_t)n * kD + c0);
            fx4 ea = row[0];
            fx4 eb = row[1];
            float pu = ea.x*dua.x + ea.y*dua.y + ea.z*dua.z + ea.w*dua.w
                     + eb.x*dub.x + eb.y*dub.y + eb.z*dub.z + eb.w*dub.w;
            float pv = ea.x*dva.x + ea.y*dva.y + ea.z*dva.z + ea.w*dva.w
                     + eb.x*dvb.x + eb.y*dvb.y + eb.z*dvb.z + eb.w*dvb.w;
            float keep = (l & 1) ? pv : pu;
            float send = (l & 1) ? pu : pv;
            float x = keep + __shfl_xor(send, 1);
            x += __shfl_xor(x, 2);
            x += __shfl_xor(x, 4);
            x += __shfl_xor(x, 8);
            float vv = __shfl_xor(x, 1);   // lane0 <- v (lane1's value)
            if (l == 0) {
                u64 pk = ((u64)__float_as_uint(vv) << 32)
                       | (u64)__float_as_uint(x);
                __hip_atomic_store((u64*)uv + n, pk, __ATOMIC_RELAXED,
                                   __HIP_MEMORY_SCOPE_AGENT);
            }
        }
    }

    // ---- dtype detect (wave-uniform, block-uniform) ----
    const u64* ei64 = (const u64*)eiv;
    u64 hiw = ei64[threadIdx.x & 63] >> 32;
    const bool is64 = (__ballot(hiw != 0ull) == 0ull);

    const float db = b[1] - b[0];
    u64* root = flags + 256;   // byte offset 2048, inside the 4KB memset

    // stripes: p = tid + k*kThreads; k=0,1,2 always < kPairs, k=3 partial
    const int p0 = tid;
    const int p1 = tid + kThreads;
    const int p2 = tid + 2 * kThreads;
    const int p3 = tid + 3 * kThreads;

    if (is64) {
        // prefetch stripes 0,1 (pinned live so they issue before the barrier)
        u64 ra0 = ei64[2 * p0],          ra1 = ei64[2 * p0 + 1];
        u64 ca0 = ei64[kEdges + 2 * p0], ca1 = ei64[kEdges + 2 * p0 + 1];
        u64 rb0 = ei64[2 * p1],          rb1 = ei64[2 * p1 + 1];
        u64 cb0 = ei64[kEdges + 2 * p1], cb1 = ei64[kEdges + 2 * p1 + 1];
        asm volatile("" :: "v"(ra0), "v"(ra1), "v"(ca0), "v"(ca1),
                           "v"(rb0), "v"(rb1), "v"(cb0), "v"(cb1));

        grid_barrier(flags, root);

        emit_pair(uv, out, db, (int)ra0, (int)ra1, (int)ca0, (int)ca1, p0);
        emit_pair(uv, out, db, (int)rb0, (int)rb1, (int)cb0, (int)cb1, p1);
        {
            u64 r0 = ei64[2 * p2],          r1 = ei64[2 * p2 + 1];
            u64 q0 = ei64[kEdges + 2 * p2], q1 = ei64[kEdges + 2 * p2 + 1];
            emit_pair(uv, out, db, (int)r0, (int)r1, (int)q0, (int)q1, p2);
        }
        if (p3 < kPairs) {
            u64 r0 = ei64[2 * p3],          r1 = ei64[2 * p3 + 1];
            u64 q0 = ei64[kEdges + 2 * p3], q1 = ei64[kEdges + 2 * p3 + 1];
            emit_pair(uv, out, db, (int)r0, (int)r1, (int)q0, (int)q1, p3);
        }
    } else {
        const u64* r64 = (const u64*)eiv;                       // int32 pairs
        const u64* c64 = (const u64*)((const int*)eiv + kEdges);
        u64 pa = r64[p0], qa = c64[p0];
        u64 pb = r64[p1], qb = c64[p1];
        asm volatile("" :: "v"(pa), "v"(qa), "v"(pb), "v"(qb));

        grid_barrier(flags, root);

        emit_pair(uv, out, db, (int)(pa & 0xffffffffull), (int)(pa >> 32),
                               (int)(qa & 0xffffffffull), (int)(qa >> 32), p0);
        emit_pair(uv, out, db, (int)(pb & 0xffffffffull), (int)(pb >> 32),
                               (int)(qb & 0xffffffffull), (int)(qb >> 32), p1);
        {
            u64 pc = r64[p2], qc = c64[p2];
            emit_pair(uv, out, db, (int)(pc & 0xffffffffull), (int)(pc >> 32),
                                   (int)(qc & 0xffffffffull), (int)(qc >> 32), p2);
        }
        if (p3 < kPairs) {
            u64 pd = r64[p3], qd = c64[p3];
            emit_pair(uv, out, db, (int)(pd & 0xffffffffull), (int)(pd >> 32),
                                   (int)(qd & 0xffffffffull), (int)(qd >> 32), p3);
        }
    }
}

// ---------------------------------------------------------------------------
// Fallback: proven R7 two-kernel path (used only if the memset errors).
// ---------------------------------------------------------------------------
__global__ __launch_bounds__(256) void node_pre(const float* __restrict__ emb,
                                                const float* __restrict__ W,
                                                float* __restrict__ uv) {
    const int l  = threadIdx.x & 15;
    const int c0 = l * 8;
    fx4 w0a = *(const fx4*)&W[c0],       w0b = *(const fx4*)&W[c0 + 4];
    fx4 w1a = *(const fx4*)&W[256 + c0], w1b = *(const fx4*)&W[256 + c0 + 4];
    fx4 dua = w1a - w0a, dub = w1b - w0b;
    fx4 w2a = *(const fx4*)&W[128 + c0], w2b = *(const fx4*)&W[128 + c0 + 4];
    fx4 w3a = *(const fx4*)&W[384 + c0], w3b = *(const fx4*)&W[384 + c0 + 4];
    fx4 dva = w3a - w2a, dvb = w3b - w2b;

    const int n = (blockIdx.x * blockDim.x + threadIdx.x) >> 4;
    if (n >= kNodes) return;
    const fx4* row = (const fx4*)(emb + (size_t)n * kD + c0);
    fx4 ea = row[0];
    fx4 eb = row[1];
    float pu = ea.x*dua.x + ea.y*dua.y + ea.z*dua.z + ea.w*dua.w
             + eb.x*dub.x + eb.y*dub.y + eb.z*dub.z + eb.w*dub.w;
    float pv = ea.x*dva.x + ea.y*dva.y + ea.z*dva.z + ea.w*dva.w
             + eb.x*dvb.x + eb.y*dvb.y + eb.z*dvb.z + eb.w*dvb.w;
    float keep = (l & 1) ? pv : pu;
    float send = (l & 1) ? pu : pv;
    float x = keep + __shfl_xor(send, 1);
    x += __shfl_xor(x, 2);
    x += __shfl_xor(x, 4);
    x += __shfl_xor(x, 8);
    if (l < 2) uv[n * 2 + l] = x;
}

__global__ __launch_bounds__(256) void edge_attn(const void* __restrict__ eiv,
                                                 const float* __restrict__ uv,
                                                 const float* __restrict__ b,
                                                 float* __restrict__ out) {
    const u64* ei64 = (const u64*)eiv;
    u64 hiw = ei64[threadIdx.x & 63] >> 32;
    const bool is64 = (__ballot(hiw != 0ull) == 0ull);

    const int e2 = blockIdx.x * blockDim.x + threadIdx.x;
    if (e2 >= kPairs) return;

    int r0, r1, c0i, c1i;
    if (is64) {
        r0  = (int)ei64[2 * e2];          r1  = (int)ei64[2 * e2 + 1];
        c0i = (int)ei64[kEdges + 2 * e2]; c1i = (int)ei64[kEdges + 2 * e2 + 1];
    } else {
        const int* ei32 = (const int*)eiv;
        r0  = ei32[2 * e2];          r1  = ei32[2 * e2 + 1];
        c0i = ei32[kEdges + 2 * e2]; c1i = ei32[kEdges + 2 * e2 + 1];
    }
    const float db = b[1] - b[0];
    float d0 = uv[2 * r0] + uv[2 * c0i + 1] + db;
    float d1 = uv[2 * r1] + uv[2 * c1i + 1] + db;
    float q0 = __builtin_amdgcn_rcpf(1.0f + __expf(d0));
    float q1 = __builtin_amdgcn_rcpf(1.0f + __expf(d1));
    fx4 o = {q0, 1.0f - q0, q1, 1.0f - q1};
    ((fx4*)out)[e2] = o;
}

extern "C" void kernel_launch(void* const* d_in, const int* in_sizes, int n_in,
                              void* d_out, int out_size, void* d_ws, size_t ws_size,
                              hipStream_t stream) {
    const float* emb = (const float*)d_in[0];
    const void*  ei  = d_in[1];
    const float* W   = (const float*)d_in[2];
    const float* b   = (const float*)d_in[3];
    float* out = (float*)d_out;

    u64*   flags = (u64*)d_ws;                      // 16 leaves @128B + root
    float* uv    = (float*)((char*)d_ws + 8192);    // 800 KB node table

    hipError_t err = hipMemsetAsync(d_ws, 0, 4096, stream);
    if (err == hipSuccess) {
        fused<<<kBlocks, 256, 0, stream>>>(emb, ei, W, b, flags, uv, out);
    } else {
        node_pre<<<(kNodes * 16 + 255) / 256, 256, 0, stream>>>(emb, W, uv);
        edge_attn<<<(kPairs + 255) / 256, 256, 0, stream>>>(ei, uv, b, out);
    }
}